// Round 9
// baseline (531.869 us; speedup 1.0000x reference)
//
#include <hip/hip_runtime.h>
#include <cmath>

#define HID 128
#define TM 64           // tile rows per block
#define MAXK 8          // max tiles a segment can span (seg len <= ~512)
#define PIECE_F 132     // floats per piece: [m, d, pad, pad, p[128]]

typedef __attribute__((ext_vector_type(8))) short bf16x8;
typedef __attribute__((ext_vector_type(4))) float f32x4;
typedef __attribute__((ext_vector_type(2))) float f32x2;
typedef __attribute__((ext_vector_type(4))) unsigned u32x4;

__device__ __forceinline__ unsigned rne_bf16_bits(float f) {
    unsigned u = __builtin_bit_cast(unsigned, f);
    return (u + 0x7FFFu + ((u >> 16) & 1u)) & 0xFFFF0000u;
}

__device__ __forceinline__ float fast_tanh(float x) {
    float e = __expf(2.0f * x);
    return 1.0f - 2.0f * __builtin_amdgcn_rcpf(e + 1.0f);
}

// Truncation split of 8 floats into bf16 hi + lo (hi+lo == f to ~2^-16 rel).
__device__ __forceinline__ void split8(const float* f, bf16x8& hi, bf16x8& lo) {
    u32x4 h, l;
    #pragma unroll
    for (int p = 0; p < 4; ++p) {
        unsigned u0 = __builtin_bit_cast(unsigned, f[2 * p]);
        unsigned u1 = __builtin_bit_cast(unsigned, f[2 * p + 1]);
        h[p] = (u0 >> 16) | (u1 & 0xFFFF0000u);
        float hf0 = __builtin_bit_cast(float, u0 & 0xFFFF0000u);
        float hf1 = __builtin_bit_cast(float, u1 & 0xFFFF0000u);
        unsigned d0 = __builtin_bit_cast(unsigned, f[2 * p] - hf0);
        unsigned d1 = __builtin_bit_cast(unsigned, f[2 * p + 1] - hf1);
        l[p] = (d0 >> 16) | (d1 & 0xFFFF0000u);
    }
    hi = __builtin_bit_cast(bf16x8, h);
    lo = __builtin_bit_cast(bf16x8, l);
}

// ---------------------------------------------------------------------------
// Prep: W -> bf16 RNE in exact 16x16x32 A-fragment order:
// id = (ks*8 + jt)*64 + lane; holds W[jt*16 + (lane&15)][ks*32 + (lane>>4)*8 + q]
// ---------------------------------------------------------------------------
__global__ __launch_bounds__(256) void prep_w_frag(
    const float* __restrict__ W, short* __restrict__ whi)
{
    int id = blockIdx.x * 256 + threadIdx.x;    // 0..2047
    int l  = id & 63;
    int jt = (id >> 6) & 7;
    int ks = id >> 9;                           // 0..3
    int j  = jt * 16 + (l & 15);
    int k0 = ks * 32 + ((l >> 4) << 3);
    const float* src = W + j * HID + k0;
    short h8[8];
    #pragma unroll
    for (int q = 0; q < 8; ++q)
        h8[q] = (short)(rne_bf16_bits(src[q]) >> 16);
    *(bf16x8*)(whi + (size_t)id * 8) = *(const bf16x8*)h8;
}

// ---------------------------------------------------------------------------
// Segment starts from sorted owners (int32/int64) + first-segment per TM-tile.
// ---------------------------------------------------------------------------
__global__ void seg_start_kernel(const int* __restrict__ ow,
                                 int* __restrict__ seg_start,
                                 int* __restrict__ fseg, int N, int S)
{
    const int is64 = (ow[(size_t)N - 1] == 0) ? 1 : 0;
    long i = (long)blockIdx.x * blockDim.x + threadIdx.x;
    if (i > N) return;
    int a = (i == 0) ? -1 : ow[is64 ? (size_t)(2 * (i - 1)) : (size_t)(i - 1)];
    int b = (i == N) ? S  : ow[is64 ? (size_t)(2 * i)       : (size_t)i];
    for (int s = a + 1; s <= b; ++s) seg_start[s] = (int)i;
    if (i < N && (i & (TM - 1)) == 0) fseg[i >> 6] = b;  // owner of row i
}

// ---------------------------------------------------------------------------
// INSTRUMENTATION BUILD: grid = 3*NT. Blocks with bIdx >= NT redo tiles
// (identical work, identical memory behavior) but write to a dummy pieces
// buffer, tripling the fused dispatch duration so it outranks the harness's
// ~300us poison fills in the rocprof top-5 and surfaces its counter row.
// Kernel body = round-7 structure (best known: 64-row tile, 4 blocks/CU,
// W-frags streamed from global, wave-per-piece phase 2 from LDS).
// ---------------------------------------------------------------------------
__global__ __launch_bounds__(256, 4) void fused_kernel(
    const float* __restrict__ X, const short* __restrict__ whi_g,
    const float* __restrict__ bproj, const float* __restrict__ wscore,
    const int* __restrict__ seg_start, const int* __restrict__ fseg,
    float* __restrict__ pieces, float* __restrict__ pieces2,
    int N, int S, int NT)
{
    __shared__ __align__(16) float X_lds[TM * HID];     // 32 KB
    __shared__ float u_lds[TM];
    __shared__ float w_lds[TM];
    __shared__ float bw_lds[2 * HID];

    const int bIdx = blockIdx.x;
    const int dup  = (bIdx >= NT);
    const int T    = dup ? ((bIdx >= 2 * NT) ? bIdx - 2 * NT : bIdx - NT) : bIdx;
    float* pout    = dup ? pieces2 : pieces;

    const int tid  = threadIdx.x;
    const int rbase = T * TM;
    const int limit = (N - rbase < TM) ? (N - rbase) : TM;

    const int lane = tid & 63;
    const int wv   = tid >> 6;
    const int l15  = lane & 15;
    const int kq   = lane >> 4;       // 0..3

    const int sseg0 = fseg[T];        // issued early
    int svl = sseg0 + lane;
    int sv  = seg_start[(svl <= S) ? svl : S];

    // --- stage X: coalesced global, swizzled LDS (8 x 16B per thread) ---
    #pragma unroll
    for (int i = 0; i < 8; ++i) {
        int id  = i * 256 + tid;          // 0..2047
        int r   = id >> 5;                // 0..63
        int c16 = id & 31;                // 16B chunk in row
        int grow = rbase + r;
        if (grow >= N) grow = N - 1;
        f32x4 v = *(const f32x4*)(X + (size_t)grow * HID + c16 * 4);
        int dst = r * HID + (((c16 >> 1) ^ (r & 7)) << 3) + ((c16 & 1) << 2);
        *(f32x4*)(&X_lds[dst]) = v;
    }
    if (tid < HID) {
        bw_lds[tid]       = bproj[tid];
        bw_lds[HID + tid] = wscore[tid];
    }
    __syncthreads();

    // ---- MFMA: v[j][i], wave owns rows i0..i0+15 ----
    const int i0 = wv * 16;
    const int r  = i0 + l15;
    f32x4 acc[8];
    #pragma unroll
    for (int jt = 0; jt < 8; ++jt)
        #pragma unroll
        for (int q = 0; q < 4; ++q) acc[jt][q] = 0.0f;

    #pragma unroll
    for (int ks = 0; ks < 4; ++ks) {
        int t = ks * 4 + kq;                       // 8-float slot index
        int lofs = r * HID + ((t ^ (r & 7)) << 3);
        float a8[8];
        *(f32x4*)(a8)     = *(const f32x4*)(&X_lds[lofs]);
        *(f32x4*)(a8 + 4) = *(const f32x4*)(&X_lds[lofs + 4]);
        bf16x8 xhi, xlo;
        split8(a8, xhi, xlo);
        #pragma unroll
        for (int jt = 0; jt < 8; ++jt) {
            bf16x8 wf = *(const bf16x8*)(
                whi_g + (size_t)(((ks * 8 + jt) * 64 + lane)) * 8);
            acc[jt] = __builtin_amdgcn_mfma_f32_16x16x32_bf16(wf, xhi, acc[jt], 0, 0, 0);
            acc[jt] = __builtin_amdgcn_mfma_f32_16x16x32_bf16(wf, xlo, acc[jt], 0, 0, 0);
        }
    }

    // ---- epilogue: u_i = sum_j w_j * tanh(v_ji + b_j) ----
    float s = 0.0f;
    #pragma unroll
    for (int jt = 0; jt < 8; ++jt)
        #pragma unroll
        for (int reg = 0; reg < 4; ++reg) {
            int j = jt * 16 + kq * 4 + reg;
            s = fmaf(fast_tanh(acc[jt][reg] + bw_lds[j]), bw_lds[HID + j], s);
        }
    s += __shfl_xor(s, 16, 64);
    s += __shfl_xor(s, 32, 64);
    if (lane < 16) u_lds[i0 + lane] = s;   // b_score cancels in softmax
    __syncthreads();

    // ---- phase 2: one wave per piece (piece <= 64 rows) ----
    const int cslot = lane >> 2;           // (2*lane)>>3
    const int coff  = 2 * (lane & 3);
    for (int i = wv; ; i += 4) {
        int st, en;
        if (i < 63) {
            st = __shfl(sv, i, 64);
            en = __shfl(sv, i + 1, 64);
        } else {
            int s0 = sseg0 + i;
            st = seg_start[(s0     <= S) ? s0     : S];
            en = seg_start[(s0 + 1 <= S) ? s0 + 1 : S];
        }
        if (st >= rbase + limit) break;    // starts monotone -> done
        if (en <= st) continue;            // empty segment
        int a  = st - rbase; if (a < 0) a = 0;
        int bb = en - rbase; if (bb > limit) bb = limit;
        if (a >= bb) continue;

        float u0 = (a + lane < bb) ? u_lds[a + lane] : -INFINITY;
        float m = u0;
        #pragma unroll
        for (int o = 32; o > 0; o >>= 1) m = fmaxf(m, __shfl_xor(m, o, 64));
        float e0 = (a + lane < bb) ? __expf(u0 - m) : 0.0f;
        float d = e0;
        #pragma unroll
        for (int o = 32; o > 0; o >>= 1) d += __shfl_xor(d, o, 64);
        if (a + lane < bb) w_lds[a + lane] = e0;

        // p[c] = sum_r e_r * x[r][c]; lane owns cols {2*lane, 2*lane+1}
        f32x2 p = {0.0f, 0.0f};
        for (int rr = a; rr < bb; rr += 4) {
            #pragma unroll
            for (int q = 0; q < 4; ++q) {
                int rq = rr + q;
                int rc = (rq < bb) ? rq : (bb - 1);
                float wq = w_lds[rc];
                wq = (rq < bb) ? wq : 0.0f;
                f32x2 xv = *(const f32x2*)(
                    &X_lds[rc * HID + ((cslot ^ (rc & 7)) << 3) + coff]);
                p.x = fmaf(wq, xv.x, p.x);
                p.y = fmaf(wq, xv.y, p.y);
            }
        }

        int sseg = sseg0 + i;
        int slot = (T - (st >> 6)) & (MAXK - 1);
        float* dst = pout + ((size_t)sseg * MAXK + slot) * PIECE_F;
        if (lane == 0) { dst[0] = m; dst[1] = d; }
        *(f32x2*)(dst + 4 + 2 * lane) = p;
    }
}

// ---------------------------------------------------------------------------
// Fixup: merge pieces per segment -> z[s][:].
// ---------------------------------------------------------------------------
__global__ __launch_bounds__(64) void fixup_kernel(
    const float* __restrict__ pieces, const int* __restrict__ seg_start,
    float* __restrict__ z)
{
    const int s = blockIdx.x;
    const int lane = threadIdx.x;
    const int start = seg_start[s];
    const int end   = seg_start[s + 1];

    if (start >= end) {
        f32x2 zo = {0.0f, 0.0f};
        *(f32x2*)(z + (size_t)s * HID + lane * 2) = zo;
        return;
    }
    int K = ((end - 1) >> 6) - (start >> 6) + 1;
    if (K > MAXK) K = MAXK;

    const float* base0 = pieces + (size_t)s * MAXK * PIECE_F;
    float M = -INFINITY;
    for (int k = 0; k < K; ++k) M = fmaxf(M, base0[k * PIECE_F]);

    float D = 0.0f;
    f32x2 zz = {0.0f, 0.0f};
    for (int k = 0; k < K; ++k) {
        const float* b = base0 + k * PIECE_F;
        float sc = __expf(b[0] - M);
        D = fmaf(b[1], sc, D);
        f32x2 pv = *(const f32x2*)(b + 4 + lane * 2);
        zz.x = fmaf(sc, pv.x, zz.x);
        zz.y = fmaf(sc, pv.y, zz.y);
    }
    float inv = 1.0f / D;
    f32x2 zo = {zz.x * inv, zz.y * inv};
    *(f32x2*)(z + (size_t)s * HID + lane * 2) = zo;
}

// ---------------------------------------------------------------------------
extern "C" void kernel_launch(void* const* d_in, const int* in_sizes, int n_in,
                              void* d_out, int out_size, void* d_ws, size_t ws_size,
                              hipStream_t stream)
{
    const float* X   = (const float*)d_in[0];
    const int*   ow  = (const int*)  d_in[1];
    const float* W   = (const float*)d_in[2];
    const float* bp  = (const float*)d_in[3];
    const float* wsc = (const float*)d_in[4];

    const int N  = in_sizes[0] / HID;
    const int S  = out_size / HID;
    const int NT = (N + TM - 1) / TM;

    const size_t piece_bytes = (size_t)S * MAXK * PIECE_F * 4;

    char* ws = (char*)d_ws;
    size_t off_seg = 0;
    size_t off_fs  = (((size_t)(S + 1) * 4) + 255) & ~(size_t)255;
    size_t off_w   = (off_fs + (size_t)NT * 4 + 255) & ~(size_t)255;
    size_t off_pc  = (off_w + (size_t)HID * HID * 2 + 255) & ~(size_t)255;
    size_t off_pc2 = (off_pc + piece_bytes + 255) & ~(size_t)255;

    int*   seg     = (int*)  (ws + off_seg);
    int*   fsg     = (int*)  (ws + off_fs);
    short* whi     = (short*)(ws + off_w);
    float* pieces  = (float*)(ws + off_pc);
    float* pieces2 = (float*)(ws + off_pc2);
    float* z       = (float*)d_out;

    const int blocksB = ((N + 1) + 255) / 256;
    seg_start_kernel<<<blocksB, 256, 0, stream>>>(ow, seg, fsg, N, S);

    prep_w_frag<<<8, 256, 0, stream>>>(W, whi);

    fused_kernel<<<3 * NT, 256, 0, stream>>>(X, whi, bp, wsc, seg, fsg,
                                             pieces, pieces2, N, S, NT);

    fixup_kernel<<<S, 64, 0, stream>>>(pieces, seg, z);
}

// Round 10
// 175.915 us; speedup vs baseline: 3.0234x; 3.0234x over previous
//
#include <hip/hip_runtime.h>
#include <cmath>

#define HID 128
#define TM 64           // tile rows per block
#define MAXK 8          // max tiles a segment can span (seg len <= ~512)
#define PIECE_F 132     // floats per piece: [m, d, pad, pad, p[128]]

typedef __attribute__((ext_vector_type(8))) short bf16x8;
typedef __attribute__((ext_vector_type(4))) float f32x4;
typedef __attribute__((ext_vector_type(2))) float f32x2;

__device__ __forceinline__ unsigned rne_bf16_bits(float f) {
    unsigned u = __builtin_bit_cast(unsigned, f);
    return (u + 0x7FFFu + ((u >> 16) & 1u)) & 0xFFFF0000u;
}

__device__ __forceinline__ float exp2_fast(float x) {
    float r;
    asm("v_exp_f32 %0, %1" : "=v"(r) : "v"(x));
    return r;
}

// tanh(x) = 1 - 2/(2^(2*log2e*x) + 1); 1 mul + 1 trans + add + rcp + fma
__device__ __forceinline__ float fast_tanh(float x) {
    float e = exp2_fast(x * 2.885390082f);
    return 1.0f - 2.0f * __builtin_amdgcn_rcpf(e + 1.0f);
}

// Pack 8 floats -> 8 bf16 (RNE).
__device__ __forceinline__ bf16x8 pack8(const float* f) {
    short h8[8];
    #pragma unroll
    for (int q = 0; q < 8; ++q)
        h8[q] = (short)(rne_bf16_bits(f[q]) >> 16);
    return *(const bf16x8*)h8;
}

// ---------------------------------------------------------------------------
// Prep: W -> bf16 RNE in exact 16x16x32 A-fragment order:
// id = (ks*8 + jt)*64 + lane; holds W[jt*16 + (lane&15)][ks*32 + (lane>>4)*8 + q]
// ---------------------------------------------------------------------------
__global__ __launch_bounds__(256) void prep_w_frag(
    const float* __restrict__ W, short* __restrict__ whi)
{
    int id = blockIdx.x * 256 + threadIdx.x;    // 0..2047
    int l  = id & 63;
    int jt = (id >> 6) & 7;
    int ks = id >> 9;                           // 0..3
    int j  = jt * 16 + (l & 15);
    int k0 = ks * 32 + ((l >> 4) << 3);
    const float* src = W + j * HID + k0;
    short h8[8];
    #pragma unroll
    for (int q = 0; q < 8; ++q)
        h8[q] = (short)(rne_bf16_bits(src[q]) >> 16);
    *(bf16x8*)(whi + (size_t)id * 8) = *(const bf16x8*)h8;
}

// ---------------------------------------------------------------------------
// Segment starts from sorted owners (int32/int64) + first-segment per TM-tile.
// ---------------------------------------------------------------------------
__global__ void seg_start_kernel(const int* __restrict__ ow,
                                 int* __restrict__ seg_start,
                                 int* __restrict__ fseg, int N, int S)
{
    const int is64 = (ow[(size_t)N - 1] == 0) ? 1 : 0;
    long i = (long)blockIdx.x * blockDim.x + threadIdx.x;
    if (i > N) return;
    int a = (i == 0) ? -1 : ow[is64 ? (size_t)(2 * (i - 1)) : (size_t)(i - 1)];
    int b = (i == N) ? S  : ow[is64 ? (size_t)(2 * i)       : (size_t)i];
    for (int s = a + 1; s <= b; ++s) seg_start[s] = (int)i;
    if (i < N && (i & (TM - 1)) == 0) fseg[i >> 6] = b;  // owner of row i
}

// ---------------------------------------------------------------------------
// Fused, 64-row tile, bf16 X in LDS (16 KB) -> 8 blocks/CU.
// X LDS layout (shorts): chunk c (8 bf16) of row r at r*128 + (c^(r&7))*8.
// All access patterns <= 2-way bank aliasing (free).
// ---------------------------------------------------------------------------
__global__ __launch_bounds__(256, 8) void fused_kernel(
    const float* __restrict__ X, const short* __restrict__ whi_g,
    const float* __restrict__ bproj, const float* __restrict__ wscore,
    const int* __restrict__ seg_start, const int* __restrict__ fseg,
    float* __restrict__ pieces, int N, int S)
{
    __shared__ __align__(16) short X_lds[TM * HID];     // 16 KB bf16
    __shared__ float u_lds[TM];
    __shared__ float w_lds[TM];
    __shared__ float bw_lds[2 * HID];

    const int tid  = threadIdx.x;
    const int bIdx = blockIdx.x;
    const int rbase = bIdx * TM;
    const int limit = (N - rbase < TM) ? (N - rbase) : TM;

    const int lane = tid & 63;
    const int wv   = tid >> 6;
    const int l15  = lane & 15;
    const int kq   = lane >> 4;       // 0..3

    const int sseg0 = fseg[bIdx];     // issued early
    int svl = sseg0 + lane;
    int sv  = seg_start[(svl <= S) ? svl : S];

    // --- stage X: read 32B f32, convert to bf16 RNE, write 16B chunk ---
    #pragma unroll
    for (int it = 0; it < 4; ++it) {
        int id = it * 256 + tid;          // 0..1023
        int r  = id >> 4;                 // 0..63
        int c  = id & 15;                 // 8-elem chunk
        int grow = rbase + r;
        if (grow >= N) grow = N - 1;
        float a8[8];
        *(f32x4*)(a8)     = *(const f32x4*)(X + (size_t)grow * HID + c * 8);
        *(f32x4*)(a8 + 4) = *(const f32x4*)(X + (size_t)grow * HID + c * 8 + 4);
        *(bf16x8*)(&X_lds[r * HID + ((c ^ (r & 7)) << 3)]) = pack8(a8);
    }
    if (tid < HID) {
        bw_lds[tid]       = bproj[tid];
        bw_lds[HID + tid] = wscore[tid];
    }
    __syncthreads();

    // ---- MFMA: v[j][i], wave owns rows i0..i0+15 ----
    const int i0 = wv * 16;
    const int r  = i0 + l15;
    f32x4 acc[8];
    #pragma unroll
    for (int jt = 0; jt < 8; ++jt)
        #pragma unroll
        for (int q = 0; q < 4; ++q) acc[jt][q] = 0.0f;

    #pragma unroll
    for (int ks = 0; ks < 4; ++ks) {
        int t = ks * 4 + kq;              // this lane's k-octet chunk
        bf16x8 xf = *(const bf16x8*)(&X_lds[r * HID + ((t ^ (r & 7)) << 3)]);
        #pragma unroll
        for (int jt = 0; jt < 8; ++jt) {
            bf16x8 wf = *(const bf16x8*)(
                whi_g + (size_t)(((ks * 8 + jt) * 64 + lane)) * 8);
            acc[jt] = __builtin_amdgcn_mfma_f32_16x16x32_bf16(wf, xf, acc[jt], 0, 0, 0);
        }
    }

    // ---- epilogue: u_i = sum_j w_j * tanh(v_ji + b_j) ----
    // D layout: col i = lane&15, row j = jt*16 + (lane>>4)*4 + reg
    float s = 0.0f;
    #pragma unroll
    for (int jt = 0; jt < 8; ++jt)
        #pragma unroll
        for (int reg = 0; reg < 4; ++reg) {
            int j = jt * 16 + kq * 4 + reg;
            s = fmaf(fast_tanh(acc[jt][reg] + bw_lds[j]), bw_lds[HID + j], s);
        }
    s += __shfl_xor(s, 16, 64);
    s += __shfl_xor(s, 32, 64);
    if (lane < 16) u_lds[i0 + lane] = s;   // b_score cancels in softmax
    __syncthreads();

    // ---- phase 2: one wave per piece (piece <= 64 rows) ----
    // lane owns cols {2*lane, 2*lane+1}: chunk cc = lane>>2, short off (lane&3)*2
    const int cc  = lane >> 2;
    const int co  = (lane & 3) << 1;
    for (int i = wv; ; i += 4) {
        int st, en;
        if (i < 63) {
            st = __shfl(sv, i, 64);
            en = __shfl(sv, i + 1, 64);
        } else {
            int s0 = sseg0 + i;
            st = seg_start[(s0     <= S) ? s0     : S];
            en = seg_start[(s0 + 1 <= S) ? s0 + 1 : S];
        }
        if (st >= rbase + limit) break;    // starts monotone -> done
        if (en <= st) continue;            // empty segment
        int a  = st - rbase; if (a < 0) a = 0;
        int bb = en - rbase; if (bb > limit) bb = limit;
        if (a >= bb) continue;

        float u0 = (a + lane < bb) ? u_lds[a + lane] : -INFINITY;
        float m = u0;
        #pragma unroll
        for (int o = 32; o > 0; o >>= 1) m = fmaxf(m, __shfl_xor(m, o, 64));
        float e0 = (a + lane < bb) ? exp2_fast((u0 - m) * 1.442695041f) : 0.0f;
        float d = e0;
        #pragma unroll
        for (int o = 32; o > 0; o >>= 1) d += __shfl_xor(d, o, 64);
        if (a + lane < bb) w_lds[a + lane] = e0;

        // p[c] = sum_r e_r * x[r][c]; unmasked quad loop + scalar tail
        f32x2 p = {0.0f, 0.0f};
        int rr = a;
        for (; rr + 4 <= bb; rr += 4) {
            #pragma unroll
            for (int q = 0; q < 4; ++q) {
                int rc = rr + q;
                float wq = w_lds[rc];
                unsigned pr = *(const unsigned*)(
                    &X_lds[rc * HID + ((cc ^ (rc & 7)) << 3) + co]);
                float x0 = __builtin_bit_cast(float, pr << 16);
                float x1 = __builtin_bit_cast(float, pr & 0xFFFF0000u);
                p.x = fmaf(wq, x0, p.x);
                p.y = fmaf(wq, x1, p.y);
            }
        }
        for (; rr < bb; ++rr) {
            float wq = w_lds[rr];
            unsigned pr = *(const unsigned*)(
                &X_lds[rr * HID + ((cc ^ (rr & 7)) << 3) + co]);
            float x0 = __builtin_bit_cast(float, pr << 16);
            float x1 = __builtin_bit_cast(float, pr & 0xFFFF0000u);
            p.x = fmaf(wq, x0, p.x);
            p.y = fmaf(wq, x1, p.y);
        }

        int sseg = sseg0 + i;
        int slot = (bIdx - (st >> 6)) & (MAXK - 1);
        float* dst = pieces + ((size_t)sseg * MAXK + slot) * PIECE_F;
        if (lane == 0) { dst[0] = m; dst[1] = d; }
        *(f32x2*)(dst + 4 + 2 * lane) = p;
    }
}

// ---------------------------------------------------------------------------
// Fixup: merge pieces per segment -> z[s][:].
// ---------------------------------------------------------------------------
__global__ __launch_bounds__(64) void fixup_kernel(
    const float* __restrict__ pieces, const int* __restrict__ seg_start,
    float* __restrict__ z)
{
    const int s = blockIdx.x;
    const int lane = threadIdx.x;
    const int start = seg_start[s];
    const int end   = seg_start[s + 1];

    if (start >= end) {
        f32x2 zo = {0.0f, 0.0f};
        *(f32x2*)(z + (size_t)s * HID + lane * 2) = zo;
        return;
    }
    int K = ((end - 1) >> 6) - (start >> 6) + 1;
    if (K > MAXK) K = MAXK;

    const float* base0 = pieces + (size_t)s * MAXK * PIECE_F;
    float M = -INFINITY;
    for (int k = 0; k < K; ++k) M = fmaxf(M, base0[k * PIECE_F]);

    float D = 0.0f;
    f32x2 zz = {0.0f, 0.0f};
    for (int k = 0; k < K; ++k) {
        const float* b = base0 + k * PIECE_F;
        float sc = __expf(b[0] - M);
        D = fmaf(b[1], sc, D);
        f32x2 pv = *(const f32x2*)(b + 4 + lane * 2);
        zz.x = fmaf(sc, pv.x, zz.x);
        zz.y = fmaf(sc, pv.y, zz.y);
    }
    float inv = 1.0f / D;
    f32x2 zo = {zz.x * inv, zz.y * inv};
    *(f32x2*)(z + (size_t)s * HID + lane * 2) = zo;
}

// ---------------------------------------------------------------------------
extern "C" void kernel_launch(void* const* d_in, const int* in_sizes, int n_in,
                              void* d_out, int out_size, void* d_ws, size_t ws_size,
                              hipStream_t stream)
{
    const float* X   = (const float*)d_in[0];
    const int*   ow  = (const int*)  d_in[1];
    const float* W   = (const float*)d_in[2];
    const float* bp  = (const float*)d_in[3];
    const float* wsc = (const float*)d_in[4];

    const int N  = in_sizes[0] / HID;
    const int S  = out_size / HID;
    const int NT = (N + TM - 1) / TM;

    char* ws = (char*)d_ws;
    size_t off_seg = 0;
    size_t off_fs  = (((size_t)(S + 1) * 4) + 255) & ~(size_t)255;
    size_t off_w   = (off_fs + (size_t)NT * 4 + 255) & ~(size_t)255;
    size_t off_pc  = (off_w + (size_t)HID * HID * 2 + 255) & ~(size_t)255;

    int*   seg    = (int*)  (ws + off_seg);
    int*   fsg    = (int*)  (ws + off_fs);
    short* whi    = (short*)(ws + off_w);
    float* pieces = (float*)(ws + off_pc);
    float* z      = (float*)d_out;

    const int blocksB = ((N + 1) + 255) / 256;
    seg_start_kernel<<<blocksB, 256, 0, stream>>>(ow, seg, fsg, N, S);

    prep_w_frag<<<8, 256, 0, stream>>>(W, whi);

    fused_kernel<<<NT, 256, 0, stream>>>(X, whi, bp, wsc, seg, fsg,
                                         pieces, N, S);

    fixup_kernel<<<S, 64, 0, stream>>>(pieces, seg, z);
}